// Round 1
// baseline (461.515 us; speedup 1.0000x reference)
//
#include <hip/hip_runtime.h>

// Problem constants
#define N_ROWS 65536   // B*H*W = 16*64*64
#define C_DIM  64
#define K_CODES 512
#define HW     4096    // H*W
#define CHW    262144  // C*H*W
#define OUT_ELEMS 4194304  // B*C*H*W

// ws layout:
//   [0,    2048) : hist, 512 x uint32
//   [2048, 2056) : sse accumulator, double
//   [4096, 6144) : enorm, 512 x float

__global__ void vq_prep(const float* __restrict__ emb,
                        unsigned* __restrict__ hist,
                        double* __restrict__ sse,
                        float* __restrict__ enorm) {
    const int k = threadIdx.x;  // 512 threads
    hist[k] = 0u;
    if (k == 0) *sse = 0.0;
    const float* e = emb + (k << 6);
    float s0 = 0.f, s1 = 0.f, s2 = 0.f, s3 = 0.f;
#pragma unroll
    for (int c = 0; c < 64; c += 4) {
        s0 = fmaf(e[c],     e[c],     s0);
        s1 = fmaf(e[c + 1], e[c + 1], s1);
        s2 = fmaf(e[c + 2], e[c + 2], s2);
        s3 = fmaf(e[c + 3], e[c + 3], s3);
    }
    enorm[k] = (s0 + s1) + (s2 + s3);
}

__launch_bounds__(256, 2)
__global__ void vq_main(const float* __restrict__ x_in,
                        const float* __restrict__ emb,
                        const float* __restrict__ enorm,
                        float* __restrict__ out,
                        float* __restrict__ idx_out,
                        unsigned* __restrict__ hist,
                        double* __restrict__ sse_acc) {
    __shared__ float  ls_b1[128];
    __shared__ float  ls_b2[128];
    __shared__ int    ls_i1[128];
    __shared__ int    ls_i2[128];
    __shared__ double ls_red[4];

    const int t    = threadIdx.x;
    const int r    = t & 127;
    const int half = t >> 7;          // 0 or 1: which half of K this thread scans
    const int n    = (blockIdx.x << 7) + r;   // global row id
    const int w    = n & 63;
    const int h    = (n >> 6) & 63;
    const int b    = n >> 12;

    // Load this row's 64 channels into registers.
    // Lane i <-> w consecutive -> each per-c load is a coalesced 256B wave access.
    const float* xp = x_in + ((size_t)b * CHW + (size_t)h * 64 + (size_t)w);
    float x[64];
#pragma unroll
    for (int c = 0; c < 64; ++c) x[c] = xp[(size_t)c * HW];

    // Scan half of the codebook. emb addresses are wave-uniform (k is a loop
    // counter, half is constant per wave since 128 % 64 == 0) -> scalar loads.
    const int k0 = half << 8;  // 0 or 256
    float B1 = 3.4e38f, B2 = 3.4e38f;
    int   I1 = 0,       I2 = 0;
    for (int kk = 0; kk < 256; ++kk) {
        const int k = k0 + kk;
        const float* e = emb + (k << 6);
        float a0 = 0.f, a1 = 0.f, a2 = 0.f, a3 = 0.f;
#pragma unroll
        for (int c = 0; c < 64; c += 4) {
            a0 = fmaf(x[c],     e[c],     a0);
            a1 = fmaf(x[c + 1], e[c + 1], a1);
            a2 = fmaf(x[c + 2], e[c + 2], a2);
            a3 = fmaf(x[c + 3], e[c + 3], a3);
        }
        const float dot = (a0 + a1) + (a2 + a3);
        const float d   = fmaf(-2.0f, dot, enorm[k]);
        if (d < B1)      { B2 = B1; I2 = I1; B1 = d; I1 = k; }
        else if (d < B2) { B2 = d;  I2 = k; }
    }

    // Merge the two K-halves (half 1 publishes, half 0 merges).
    if (half) { ls_b1[r] = B1; ls_b2[r] = B2; ls_i1[r] = I1; ls_i2[r] = I2; }
    __syncthreads();

    double sse_local = 0.0;
    if (half == 0) {
        const float c1 = ls_b1[r]; const int j1 = ls_i1[r];
        const float c2 = ls_b2[r]; const int j2 = ls_i2[r];
        // Our indices are all < theirs, so on exact ties ours must win (argmin
        // takes the first occurrence): strict < keeps ours on ties.
        if (c1 < B1)      { B2 = B1; I2 = I1; B1 = c1; I1 = j1; }
        else if (c1 < B2) { B2 = c1; I2 = j1; }
        if (c2 < B2)      { B2 = c2; I2 = j2; }

        // fp64 tie refinement: fp32 scan noise is ~1e-4; if the top-2 gap is
        // below 1e-2, rescore both candidates exactly and apply the
        // lowest-index-wins tie rule, matching a float64 numpy argmin.
        if (B2 - B1 < 1e-2f) {
            const float* e1 = emb + (I1 << 6);
            const float* e2 = emb + (I2 << 6);
            double d1 = 0.0, d2 = 0.0;
#pragma unroll
            for (int c = 0; c < 64; ++c) {
                const double xv = (double)x[c];
                const double t1 = xv - (double)e1[c];
                const double t2 = xv - (double)e2[c];
                d1 = fma(t1, t1, d1);
                d2 = fma(t2, t2, d2);
            }
            if (d2 < d1 || (d2 == d1 && I2 < I1)) I1 = I2;
        }

        // Epilogue: write quantized row (BCHW, coalesced along w per c),
        // accumulate commitment SSE in fp64.
        const float* eq = emb + (I1 << 6);
        float* op = out + ((size_t)b * CHW + (size_t)h * 64 + (size_t)w);
#pragma unroll
        for (int c = 0; c < 64; ++c) {
            const float qc = eq[c];
            const float dx = qc - x[c];
            sse_local += (double)dx * (double)dx;
            op[(size_t)c * HW] = qc;
        }
        atomicAdd(&hist[I1], 1u);
        idx_out[n] = (float)I1;
    }

    // Block-level fp64 SSE reduction -> one atomic per block.
#pragma unroll
    for (int off = 32; off > 0; off >>= 1)
        sse_local += __shfl_down(sse_local, off, 64);
    if ((t & 63) == 0) ls_red[t >> 6] = sse_local;
    __syncthreads();
    if (t == 0) {
        const double s = (ls_red[0] + ls_red[1]) + (ls_red[2] + ls_red[3]);
        atomicAdd(sse_acc, s);
    }
}

__global__ void vq_final(const unsigned* __restrict__ hist,
                         const double* __restrict__ sse,
                         const float* __restrict__ weight,
                         float* __restrict__ scal) {
    __shared__ double red[8];
    __shared__ int    redi[8];
    const int k = threadIdx.x;  // 512 threads
    const double p = (double)hist[k] / 65536.0;
    double term = p * log(p + 1e-10);
    int act = (weight[k] >= 0.01f) ? 1 : 0;
#pragma unroll
    for (int off = 32; off > 0; off >>= 1) {
        term += __shfl_down(term, off, 64);
        act  += __shfl_down(act,  off, 64);
    }
    if ((k & 63) == 0) { red[k >> 6] = term; redi[k >> 6] = act; }
    __syncthreads();
    if (k == 0) {
        double s = 0.0; int a = 0;
#pragma unroll
        for (int i = 0; i < 8; ++i) { s += red[i]; a += redi[i]; }
        scal[0] = (float)(sse[0] / 4194304.0);  // commitment_loss
        scal[1] = (float)exp(-s);               // perplexity
        scal[2] = (float)a;                     // active_codes
    }
}

extern "C" void kernel_launch(void* const* d_in, const int* in_sizes, int n_in,
                              void* d_out, int out_size, void* d_ws, size_t ws_size,
                              hipStream_t stream) {
    const float* x      = (const float*)d_in[0];  // [16,64,64,64] fp32
    const float* emb    = (const float*)d_in[1];  // [512,64] fp32
    const float* weight = (const float*)d_in[2];  // [512] fp32

    float* out = (float*)d_out;
    unsigned* hist = (unsigned*)d_ws;
    double*   sse  = (double*)((char*)d_ws + 2048);
    float*    enorm = (float*)((char*)d_ws + 4096);

    float* scal    = out + OUT_ELEMS;      // commitment, perplexity, active
    float* idx_out = out + OUT_ELEMS + 3;  // indices as float [65536]

    vq_prep <<<1, 512, 0, stream>>>(emb, hist, sse, enorm);
    vq_main <<<512, 256, 0, stream>>>(x, emb, enorm, out, idx_out, hist, sse);
    vq_final<<<1, 512, 0, stream>>>(hist, sse, weight, scal);
}

// Round 2
// 223.400 us; speedup vs baseline: 2.0659x; 2.0659x over previous
//
#include <hip/hip_runtime.h>

// Problem constants
#define N_ROWS 65536   // B*H*W = 16*64*64
#define C_DIM  64
#define K_CODES 512
#define HW     4096    // H*W
#define CHW    262144  // C*H*W
#define OUT_ELEMS 4194304  // B*C*H*W
#define FLT_BIG 3.4e38f

// ws layout:
//   [0,    2048) : hist, 512 x uint32
//   [2048, 2056) : sse accumulator, double
//   [4096, 6144) : enorm, 512 x float

__global__ void vq_prep(const float* __restrict__ emb,
                        unsigned* __restrict__ hist,
                        double* __restrict__ sse,
                        float* __restrict__ enorm) {
    const int k = threadIdx.x;  // 512 threads
    hist[k] = 0u;
    if (k == 0) *sse = 0.0;
    const float* e = emb + (k << 6);
    float s0 = 0.f, s1 = 0.f, s2 = 0.f, s3 = 0.f;
#pragma unroll
    for (int c = 0; c < 64; c += 4) {
        s0 = fmaf(e[c],     e[c],     s0);
        s1 = fmaf(e[c + 1], e[c + 1], s1);
        s2 = fmaf(e[c + 2], e[c + 2], s2);
        s3 = fmaf(e[c + 3], e[c + 3], s3);
    }
    enorm[k] = (s0 + s1) + (s2 + s3);
}

// Block: 256 threads = 4 waves, 64 rows/block (row = lane).
// Wave w scans K-chunk [128w, 128w+128) for all 64 rows.
// Grid: 65536/64 = 1024 blocks -> 16 waves/CU.
__global__ __launch_bounds__(256, 4)
void vq_main(const float* __restrict__ x_in,
             const float* __restrict__ emb,
             const float* __restrict__ enorm,
             float* __restrict__ out,
             float* __restrict__ idx_out,
             unsigned* __restrict__ hist,
             double* __restrict__ sse_acc) {
    __shared__ float  ls_b1[3][64];
    __shared__ float  ls_b2[3][64];
    __shared__ int    ls_i1[3][64];
    __shared__ int    ls_i2[3][64];
    __shared__ int    ls_idx[64];
    __shared__ double ls_red[4];

    const int t    = threadIdx.x;
    const int lane = t & 63;     // row within block, and w coordinate
    const int wv   = t >> 6;     // wave id 0..3 = K-chunk id
    const int n    = (blockIdx.x << 6) + lane;   // global row
    const int hh   = blockIdx.x & 63;
    const int b    = blockIdx.x >> 6;

    // Load this row's 64 channels into registers (lane <-> w, coalesced per c).
    const float* xp = x_in + ((size_t)b * CHW + (size_t)hh * 64 + (size_t)lane);
    float x[64];
#pragma unroll
    for (int c = 0; c < 64; ++c) x[c] = xp[(size_t)c * HW];
    // Pin x into VGPRs: stop the compiler from rematerializing these loads
    // inside the k-loop (round-1: VGPR_Count=64 proved it did exactly that).
#pragma unroll
    for (int c = 0; c < 64; ++c) { asm volatile("" : "+v"(x[c])); }

    // K-chunk base: force SGPR so emb/enorm addresses are provably
    // wave-uniform -> s_load (scalar pipe), not per-lane global_load.
    const int kbase = __builtin_amdgcn_readfirstlane(wv << 7);

    float B1 = FLT_BIG, B2 = FLT_BIG;
    int   I1 = 0,       I2 = 0;
    for (int kk = 0; kk < 128; ++kk) {
        const int k = kbase + kk;
        const float* e = emb + (k << 6);
        float a0 = 0.f, a1 = 0.f, a2 = 0.f, a3 = 0.f;
#pragma unroll
        for (int c = 0; c < 64; c += 4) {
            a0 = fmaf(x[c],     e[c],     a0);
            a1 = fmaf(x[c + 1], e[c + 1], a1);
            a2 = fmaf(x[c + 2], e[c + 2], a2);
            a3 = fmaf(x[c + 3], e[c + 3], a3);
        }
        const float dot = (a0 + a1) + (a2 + a3);
        const float d   = fmaf(-2.0f, dot, enorm[k]);
        if (d < B1)      { B2 = B1; I2 = I1; B1 = d; I1 = k; }
        else if (d < B2) { B2 = d;  I2 = k; }
    }

    // Publish waves 1..3, wave 0 merges in chunk order (strict < keeps the
    // lower index on ties == argmin first-occurrence).
    if (wv) {
        ls_b1[wv - 1][lane] = B1; ls_b2[wv - 1][lane] = B2;
        ls_i1[wv - 1][lane] = I1; ls_i2[wv - 1][lane] = I2;
    }
    __syncthreads();

    if (wv == 0) {
#pragma unroll
        for (int m = 0; m < 3; ++m) {
            const float c1 = ls_b1[m][lane]; const int j1 = ls_i1[m][lane];
            const float c2 = ls_b2[m][lane]; const int j2 = ls_i2[m][lane];
            if (c1 < B1)      { B2 = B1; I2 = I1; B1 = c1; I1 = j1; }
            else if (c1 < B2) { B2 = c1; I2 = j1; }
            if (c2 < B2)      { B2 = c2; I2 = j2; }
        }
        // fp64 tie refinement: fp32 noise ~1e-4; rescue when gap < 1e-2.
        if (B2 - B1 < 1e-2f) {
            const float* e1 = emb + (I1 << 6);
            const float* e2 = emb + (I2 << 6);
            double d1 = 0.0, d2 = 0.0;
#pragma unroll
            for (int c = 0; c < 64; ++c) {
                const double xv = (double)x[c];
                const double t1 = xv - (double)e1[c];
                const double t2 = xv - (double)e2[c];
                d1 = fma(t1, t1, d1);
                d2 = fma(t2, t2, d2);
            }
            if (d2 < d1 || (d2 == d1 && I2 < I1)) I1 = I2;
        }
        ls_idx[lane] = I1;
        atomicAdd(&hist[I1], 1u);
        idx_out[n] = (float)I1;
    }
    __syncthreads();

    // Epilogue, all 4 waves: wave wv writes c in [16wv, 16wv+16) for its row
    // (row = lane -> w coordinate -> coalesced stores per c).
    const int qi = ls_idx[lane];
    const float* eq = emb + (qi << 6);
    float* op = out + ((size_t)b * CHW + (size_t)hh * 64 + (size_t)lane);
    const int c0 = wv << 4;
    double sse_local = 0.0;
#pragma unroll
    for (int cc = 0; cc < 16; ++cc) {
        const int c = c0 + cc;
        const float qc = eq[c];
        const float dx = qc - x[c];
        sse_local += (double)dx * (double)dx;
        op[(size_t)c * HW] = qc;
    }

    // Block fp64 SSE reduction -> one atomic per block.
#pragma unroll
    for (int off = 32; off > 0; off >>= 1)
        sse_local += __shfl_down(sse_local, off, 64);
    if (lane == 0) ls_red[wv] = sse_local;
    __syncthreads();
    if (t == 0) {
        const double s = (ls_red[0] + ls_red[1]) + (ls_red[2] + ls_red[3]);
        atomicAdd(sse_acc, s);
    }
}

__global__ void vq_final(const unsigned* __restrict__ hist,
                         const double* __restrict__ sse,
                         const float* __restrict__ weight,
                         float* __restrict__ scal) {
    __shared__ double red[8];
    __shared__ int    redi[8];
    const int k = threadIdx.x;  // 512 threads
    const double p = (double)hist[k] / 65536.0;
    double term = p * log(p + 1e-10);
    int act = (weight[k] >= 0.01f) ? 1 : 0;
#pragma unroll
    for (int off = 32; off > 0; off >>= 1) {
        term += __shfl_down(term, off, 64);
        act  += __shfl_down(act,  off, 64);
    }
    if ((k & 63) == 0) { red[k >> 6] = term; redi[k >> 6] = act; }
    __syncthreads();
    if (k == 0) {
        double s = 0.0; int a = 0;
#pragma unroll
        for (int i = 0; i < 8; ++i) { s += red[i]; a += redi[i]; }
        scal[0] = (float)(sse[0] / 4194304.0);  // commitment_loss
        scal[1] = (float)exp(-s);               // perplexity
        scal[2] = (float)a;                     // active_codes
    }
}

extern "C" void kernel_launch(void* const* d_in, const int* in_sizes, int n_in,
                              void* d_out, int out_size, void* d_ws, size_t ws_size,
                              hipStream_t stream) {
    const float* x      = (const float*)d_in[0];  // [16,64,64,64] fp32
    const float* emb    = (const float*)d_in[1];  // [512,64] fp32
    const float* weight = (const float*)d_in[2];  // [512] fp32

    float* out = (float*)d_out;
    unsigned* hist = (unsigned*)d_ws;
    double*   sse  = (double*)((char*)d_ws + 2048);
    float*    enorm = (float*)((char*)d_ws + 4096);

    float* scal    = out + OUT_ELEMS;      // commitment, perplexity, active
    float* idx_out = out + OUT_ELEMS + 3;  // indices as float [65536]

    vq_prep <<<1, 512, 0, stream>>>(emb, hist, sse, enorm);
    vq_main <<<1024, 256, 0, stream>>>(x, emb, enorm, out, idx_out, hist, sse);
    vq_final<<<1, 512, 0, stream>>>(hist, sse, weight, scal);
}

// Round 3
// 179.773 us; speedup vs baseline: 2.5672x; 1.2427x over previous
//
#include <hip/hip_runtime.h>

// Problem constants
#define HW     4096       // H*W
#define CHW    262144     // C*H*W
#define OUT_ELEMS 4194304 // B*C*H*W
#define FLT_BIG 3.4e38f
#define ESS 132           // es LDS stride (132 ≡ 4 mod 32 -> staging writes stride-1 in k; 16B-aligned rows)

// ws layout:
//   [0,    2048) : hist, 512 x uint32
//   [2048, 2056) : sse accumulator, double
//   [2056, 2060) : done counter, uint32
//   [4096, 6144) : enorm, 512 x float

__global__ void vq_prep(const float* __restrict__ emb,
                        unsigned* __restrict__ hist,
                        double* __restrict__ sse,
                        unsigned* __restrict__ done,
                        float* __restrict__ enorm) {
    const int k = threadIdx.x;  // 512 threads
    hist[k] = 0u;
    if (k == 0) { *sse = 0.0; *done = 0u; }
    const float* e = emb + (k << 6);
    float s0 = 0.f, s1 = 0.f, s2 = 0.f, s3 = 0.f;
#pragma unroll
    for (int c = 0; c < 64; c += 4) {
        s0 = fmaf(e[c],     e[c],     s0);
        s1 = fmaf(e[c + 1], e[c + 1], s1);
        s2 = fmaf(e[c + 2], e[c + 2], s2);
        s3 = fmaf(e[c + 3], e[c + 3], s3);
    }
    enorm[k] = (s0 + s1) + (s2 + s3);
}

// Block: 256 threads, 64 rows (one (b,h) stripe; row = w).
// Thread (rq = t&15, ko = t>>4) owns rows [4rq,4rq+4) x codes [8ko,8ko+8)
// within each 128-code chunk. Grid: 1024 blocks.
__global__ __attribute__((amdgpu_flat_work_group_size(256, 256),
                          amdgpu_waves_per_eu(3, 3)))
void vq_main(const float* __restrict__ x_in, const float* __restrict__ emb,
             const float* __restrict__ enorm, float* __restrict__ out,
             float* __restrict__ idx_out, unsigned* __restrict__ hist,
             double* __restrict__ sse_acc, unsigned* __restrict__ done,
             const float* __restrict__ weight, float* __restrict__ scal) {
    __shared__ float  xs[64 * 64];    // xs[c*64 + r]  (16 KB)
    __shared__ float  es[64 * ESS];   // es[c*ESS + k] (33 KB; merge arrays overlaid later)
    __shared__ int    ls_idx[64];
    __shared__ double ls_red[4];
    __shared__ int    ls_ired[4];
    __shared__ int    ls_flag;

    const int t  = threadIdx.x;
    const int rq = t & 15;
    const int ko = t >> 4;
    const int bh = blockIdx.x;
    const int b  = bh >> 6;
    const int h  = bh & 63;
    const float* xbase = x_in + ((size_t)b * CHW + h * 64);

    // Stage xs: x is BCHW -> x[b][c][h][0..63] is already [c][row]-major.
    // lane<->r coalesced float4 global reads, stride-1 LDS writes (conflict-free).
#pragma unroll
    for (int i = 0; i < 4; ++i) {
        const int id = t + (i << 8);       // 0..1023 float4s
        const int c  = id >> 4;
        const int r4 = (id & 15) << 2;
        const float4 v = *(const float4*)(xbase + (size_t)c * HW + r4);
        *(float4*)(xs + (c << 6) + r4) = v;
    }

    float B1[4], B2[4]; int I1[4], I2[4];
#pragma unroll
    for (int r = 0; r < 4; ++r) { B1[r] = FLT_BIG; B2[r] = FLT_BIG; I1[r] = 1 << 30; I2[r] = 1 << 30; }

    for (int cb = 0; cb < 4; ++cb) {
        const int kbase = cb << 7;
        __syncthreads();
        // Stage es[c][k], k in [0,128): global reads lane<->k (uncoalesced but
        // L2-hot, emb is 128 KB); LDS writes stride-1 in k -> conflict-free.
#pragma unroll
        for (int i = 0; i < 8; ++i) {
            const int v  = t + (i << 8);   // 0..2047
            const int k  = v & 127;
            const int c0 = (v >> 7) << 2;
            const float4 ev = *(const float4*)(emb + ((size_t)(kbase + k) << 6) + c0);
            es[(c0    ) * ESS + k] = ev.x;
            es[(c0 + 1) * ESS + k] = ev.y;
            es[(c0 + 2) * ESS + k] = ev.z;
            es[(c0 + 3) * ESS + k] = ev.w;
        }
        __syncthreads();

        float acc[4][8];
#pragma unroll
        for (int r = 0; r < 4; ++r)
#pragma unroll
            for (int j = 0; j < 8; ++j) acc[r][j] = 0.f;

#pragma unroll 4
        for (int c = 0; c < 64; ++c) {
            const float4 xv = *(const float4*)(xs + (c << 6) + (rq << 2));
            const float4 e0 = *(const float4*)(es + c * ESS + (ko << 3));
            const float4 e1 = *(const float4*)(es + c * ESS + (ko << 3) + 4);
            const float xr[4] = {xv.x, xv.y, xv.z, xv.w};
            const float ee[8] = {e0.x, e0.y, e0.z, e0.w, e1.x, e1.y, e1.z, e1.w};
#pragma unroll
            for (int r = 0; r < 4; ++r)
#pragma unroll
                for (int j = 0; j < 8; ++j)
                    acc[r][j] = fmaf(xr[r], ee[j], acc[r][j]);
        }

        // d = enorm - 2*dot; update top-2 per row (codes scanned in ascending
        // order per thread -> strict < preserves first-occurrence argmin).
        const float4 n0 = *(const float4*)(enorm + kbase + (ko << 3));
        const float4 n1 = *(const float4*)(enorm + kbase + (ko << 3) + 4);
        const float nn[8] = {n0.x, n0.y, n0.z, n0.w, n1.x, n1.y, n1.z, n1.w};
#pragma unroll
        for (int j = 0; j < 8; ++j) {
            const int kg = kbase + (ko << 3) + j;
#pragma unroll
            for (int r = 0; r < 4; ++r) {
                const float d = fmaf(-2.f, acc[r][j], nn[j]);
                if (d < B1[r])      { B2[r] = B1[r]; I2[r] = I1[r]; B1[r] = d; I1[r] = kg; }
                else if (d < B2[r]) { B2[r] = d; I2[r] = kg; }
            }
        }
    }

    __syncthreads();  // chunk reads done -> overlay merge arrays on es space
    float* md1 = es;
    float* md2 = es + 1024;
    int*   mi1 = (int*)(es + 2048);
    int*   mi2 = (int*)(es + 3072);
#pragma unroll
    for (int rr = 0; rr < 4; ++rr) {
        const int row = (rq << 2) + rr;
        md1[(row << 4) + ko] = B1[rr]; mi1[(row << 4) + ko] = I1[rr];
        md2[(row << 4) + ko] = B2[rr]; mi2[(row << 4) + ko] = I2[rr];
    }
    __syncthreads();

    if (t < 64) {
        const int row = t;
        float b1 = FLT_BIG, b2 = FLT_BIG; int i1 = 1 << 30, i2 = 1 << 30;
        for (int m = 0; m < 16; ++m) {
            // candidates cover disjoint code sets; explicit index tie-break
            // gives first-occurrence semantics in any merge order
            float d = md1[(row << 4) + m]; int ii = mi1[(row << 4) + m];
            if (d < b1 || (d == b1 && ii < i1))      { b2 = b1; i2 = i1; b1 = d; i1 = ii; }
            else if (d < b2 || (d == b2 && ii < i2)) { b2 = d; i2 = ii; }
            d = md2[(row << 4) + m]; ii = mi2[(row << 4) + m];
            if (d < b2 || (d == b2 && ii < i2))      { b2 = d; i2 = ii; }
        }
        // fp64 tie refinement when fp32 gap is within noise
        if (b2 - b1 < 1e-2f) {
            const float* e1p = emb + ((size_t)i1 << 6);
            const float* e2p = emb + ((size_t)i2 << 6);
            double d1 = 0.0, d2 = 0.0;
            for (int c = 0; c < 64; ++c) {
                const double xv = (double)xs[(c << 6) + row];
                const double t1 = xv - (double)e1p[c];
                const double t2 = xv - (double)e2p[c];
                d1 = fma(t1, t1, d1);
                d2 = fma(t2, t2, d2);
            }
            if (d2 < d1 || (d2 == d1 && i2 < i1)) i1 = i2;
        }
        ls_idx[row] = i1;
        atomicAdd(&hist[i1], 1u);
        idx_out[(bh << 6) + row] = (float)i1;
    }
    __syncthreads();

    // Epilogue: wave wv writes c in [16wv,16wv+16) for row r = t&63 (coalesced
    // along w per c); fp64 SSE accumulate.
    const int r  = t & 63;
    const int wv = t >> 6;
    const int qi = ls_idx[r];
    const float* eq = emb + ((size_t)qi << 6);
    float* op = out + ((size_t)b * CHW + h * 64 + r);
    const int c0 = wv << 4;
    double sse_local = 0.0;
#pragma unroll
    for (int cc = 0; cc < 16; ++cc) {
        const int c = c0 + cc;
        const float qc = eq[c];
        const float dx = qc - xs[(c << 6) + r];
        sse_local += (double)dx * (double)dx;
        op[(size_t)c * HW] = qc;
    }
#pragma unroll
    for (int off = 32; off > 0; off >>= 1)
        sse_local += __shfl_down(sse_local, off, 64);
    if (r == 0) ls_red[wv] = sse_local;
    __syncthreads();
    if (t == 0) {
        atomicAdd(sse_acc, (ls_red[0] + ls_red[1]) + (ls_red[2] + ls_red[3]));
        __threadfence();
        const unsigned old = atomicAdd(done, 1u);
        ls_flag = (old == gridDim.x - 1) ? 1 : 0;
    }
    __syncthreads();

    // Last block computes the scalars (saves a dispatch + its launch gap).
    if (ls_flag) {
        __threadfence();
        double term = 0.0; int act = 0;
#pragma unroll
        for (int j = 0; j < 2; ++j) {
            const int k = t + (j << 8);
            // read hist through the coherent point (XCD L2s are not coherent)
            const double p = (double)atomicAdd(&hist[k], 0u) / 65536.0;
            term += p * log(p + 1e-10);
            act  += (weight[k] >= 0.01f) ? 1 : 0;
        }
#pragma unroll
        for (int off = 32; off > 0; off >>= 1) {
            term += __shfl_down(term, off, 64);
            act  += __shfl_down(act,  off, 64);
        }
        if (r == 0) { ls_red[wv] = term; ls_ired[wv] = act; }
        __syncthreads();
        if (t == 0) {
            const double s = (ls_red[0] + ls_red[1]) + (ls_red[2] + ls_red[3]);
            const int    a = ls_ired[0] + ls_ired[1] + ls_ired[2] + ls_ired[3];
            const double sse_tot = atomicAdd(sse_acc, 0.0);
            scal[0] = (float)(sse_tot / 4194304.0);  // commitment_loss
            scal[1] = (float)exp(-s);                // perplexity
            scal[2] = (float)a;                      // active_codes
        }
    }
}

extern "C" void kernel_launch(void* const* d_in, const int* in_sizes, int n_in,
                              void* d_out, int out_size, void* d_ws, size_t ws_size,
                              hipStream_t stream) {
    const float* x      = (const float*)d_in[0];  // [16,64,64,64] fp32
    const float* emb    = (const float*)d_in[1];  // [512,64] fp32
    const float* weight = (const float*)d_in[2];  // [512] fp32

    float* out = (float*)d_out;
    unsigned* hist  = (unsigned*)d_ws;
    double*   sse   = (double*)((char*)d_ws + 2048);
    unsigned* done  = (unsigned*)((char*)d_ws + 2056);
    float*    enorm = (float*)((char*)d_ws + 4096);

    float* scal    = out + OUT_ELEMS;      // commitment, perplexity, active
    float* idx_out = out + OUT_ELEMS + 3;  // indices as float [65536]

    vq_prep<<<1, 512, 0, stream>>>(emb, hist, sse, done, enorm);
    vq_main<<<1024, 256, 0, stream>>>(x, emb, enorm, out, idx_out, hist, sse,
                                      done, weight, scal);
}

// Round 4
// 169.125 us; speedup vs baseline: 2.7288x; 1.0630x over previous
//
#include <hip/hip_runtime.h>

// Problem constants
#define HW 4096           // H*W
#define CHW 262144        // C*H*W
#define OUT_ELEMS 4194304 // B*C*H*W
#define FLT_BIG 3.4e38f
#define LSTR 136          // LDS row stride (bf16 elems): 128 data + 8 pad
                          // 136 shorts = 68 dwords; 68%32=4 -> rows r,r+8 share banks (2-way = free)

typedef __attribute__((ext_vector_type(8))) short  short8;   // 8 bf16 = 1 MFMA operand frag
typedef __attribute__((ext_vector_type(4))) float  floatx4;  // MFMA C/D frag
typedef __attribute__((ext_vector_type(4))) int    intx4;

// ws layout: [0,2048) hist u32[512]; [2048,2056) sse double; [2056,2060) done u32
// (zeroed via hipMemsetAsync before the kernel - no poison assumptions)

__device__ __forceinline__ unsigned bf16_rne(float f) {
    unsigned u = __float_as_uint(f);
    return (u + 0x7FFFu + ((u >> 16) & 1u)) >> 16;  // round-to-nearest-even bf16 bits
}

// split 8 floats into hi/lo bf16 planes, packed 2-per-dword
__device__ __forceinline__ void split8(const float* f, intx4* hi, intx4* lo) {
    unsigned h[4], l[4];
#pragma unroll
    for (int j = 0; j < 4; ++j) {
        const unsigned h0 = bf16_rne(f[2 * j]);
        const unsigned h1 = bf16_rne(f[2 * j + 1]);
        const float hf0 = __uint_as_float(h0 << 16);
        const float hf1 = __uint_as_float(h1 << 16);
        const unsigned l0 = bf16_rne(f[2 * j] - hf0);
        const unsigned l1 = bf16_rne(f[2 * j + 1] - hf1);
        h[j] = h0 | (h1 << 16);
        l[j] = l0 | (l1 << 16);
    }
    *hi = intx4{(int)h[0], (int)h[1], (int)h[2], (int)h[3]};
    *lo = intx4{(int)l[0], (int)l[1], (int)l[2], (int)l[3]};
}

// Block: 256 threads = 4 waves; 128 rows x 512 codes (8 chunks of 64).
// Wave wv: rows [32wv, 32wv+32) = two 16-row M-tiles x four 16-code N-tiles.
// GEMM: dot = xh*eh + xh*el + xl*eh  (split-bf16, K=192 synthesized by
// address remap of the un-duplicated [xh|xl] / [eh|el] LDS tables).
__global__ __launch_bounds__(256)
void vq_fused(const float* __restrict__ x_in, const float* __restrict__ emb,
              const float* __restrict__ weight, float* __restrict__ out,
              float* __restrict__ idx_out, unsigned* __restrict__ hist,
              double* __restrict__ sse_acc, unsigned* __restrict__ done,
              float* __restrict__ scal) {
    __shared__ short  As[128 * LSTR];  // As[r][k]: k 0..63 = xh, 64..127 = xl   (34.8 KB)
    __shared__ short  Bs[64 * LSTR];   // Bs[n][k]: k 0..63 = eh, 64..127 = el   (17.4 KB)
    __shared__ float  en_s[512];
    __shared__ float  b1s[128], b2s[128];
    __shared__ int    i1s[128], i2s[128];
    __shared__ int    qidx[128];
    __shared__ double ls_red[4];
    __shared__ int    ls_ired[4];
    __shared__ int    ls_flag;

    const int t    = threadIdx.x;
    const int lane = t & 63;
    const int wv   = t >> 6;
    const int col  = lane & 15;
    const int quad = lane >> 4;
    const int blk  = blockIdx.x;      // 512 blocks, 128 rows each

    // ---- Phase 0: stage A (x -> hi/lo bf16) + enorm ----
    {
        const int r  = t & 127;            // row in block
        const int ch = t >> 7;             // c-half
        const int bh = 2 * blk + (r >> 6);
        const int bb = bh >> 6, hh = bh & 63, ww = r & 63;
        const float* xp = x_in + ((size_t)bb * CHW + (size_t)hh * 64 + ww);
        const int c0 = ch << 5;
#pragma unroll
        for (int cc = 0; cc < 32; cc += 8) {
            float f[8];
#pragma unroll
            for (int j = 0; j < 8; ++j) f[j] = xp[(size_t)(c0 + cc + j) * HW];  // coalesced per j
            intx4 hi, lo;
            split8(f, &hi, &lo);
            *(intx4*)&As[r * LSTR + c0 + cc]      = hi;
            *(intx4*)&As[r * LSTR + 64 + c0 + cc] = lo;
        }
        // enorm: thread handles codes t and t+256 (fp32, same as prior rounds)
#pragma unroll
        for (int rep = 0; rep < 2; ++rep) {
            const int k = t + (rep << 8);
            const float4* e4 = (const float4*)(emb + ((size_t)k << 6));
            float s0 = 0.f, s1 = 0.f, s2 = 0.f, s3 = 0.f;
#pragma unroll
            for (int i = 0; i < 16; ++i) {
                const float4 v = e4[i];
                s0 = fmaf(v.x, v.x, s0); s1 = fmaf(v.y, v.y, s1);
                s2 = fmaf(v.z, v.z, s2); s3 = fmaf(v.w, v.w, s3);
            }
            en_s[k] = (s0 + s1) + (s2 + s3);
        }
    }

    // ---- Phase 1: code-chunk loop: stage B chunk, MFMA, per-lane top-2 ----
    float B1[8], B2[8]; int I1[8], I2[8];
#pragma unroll
    for (int s = 0; s < 8; ++s) { B1[s] = FLT_BIG; B2[s] = FLT_BIG; I1[s] = 0x3FFFFFFF; I2[s] = 0x3FFFFFFF; }

    static const int kAoff[6] = {0, 32, 0, 32, 64, 96};  // xh,xh,xh,xh,xl,xl
    static const int kBoff[6] = {0, 32, 64, 96, 0, 32};  // eh,eh,el,el,eh,eh
    const int mb = wv << 5;

    for (int nc = 0; nc < 8; ++nc) {
        const int K0 = nc << 6;
        __syncthreads();  // As ready (nc=0) / prior chunk's frag reads done (nc>0)
        {   // stage B: thread (n = t>>2, cq = t&3) loads 16 c of code K0+n
            const int n  = t >> 2;
            const int c0 = (t & 3) << 4;
            const float* ep = emb + (((size_t)(K0 + n)) << 6) + c0;
#pragma unroll
            for (int cc = 0; cc < 16; cc += 8) {
                float f[8];
#pragma unroll
                for (int j = 0; j < 8; ++j) f[j] = ep[cc + j];
                intx4 hi, lo;
                split8(f, &hi, &lo);
                *(intx4*)&Bs[n * LSTR + c0 + cc]      = hi;
                *(intx4*)&Bs[n * LSTR + 64 + c0 + cc] = lo;
            }
        }
        __syncthreads();

        floatx4 acc[2][4];
#pragma unroll
        for (int mt = 0; mt < 2; ++mt)
#pragma unroll
            for (int nt = 0; nt < 4; ++nt) acc[mt][nt] = floatx4{0.f, 0.f, 0.f, 0.f};

#pragma unroll
        for (int kt = 0; kt < 6; ++kt) {
            const short* ap = &As[(mb + col) * LSTR + kAoff[kt] + (quad << 3)];
            const short8 a0 = *(const short8*)ap;
            const short8 a1 = *(const short8*)(ap + 16 * LSTR);
#pragma unroll
            for (int nt = 0; nt < 4; ++nt) {
                const short8 bv = *(const short8*)&Bs[((nt << 4) + col) * LSTR + kBoff[kt] + (quad << 3)];
                acc[0][nt] = __builtin_amdgcn_mfma_f32_16x16x32_bf16(a0, bv, acc[0][nt], 0, 0, 0);
                acc[1][nt] = __builtin_amdgcn_mfma_f32_16x16x32_bf16(a1, bv, acc[1][nt], 0, 0, 0);
            }
        }

        // top-2 update. C/D layout: col = lane&15 (code), row = quad*4 + reg.
        // Codes ascend (nc outer, nt inner) -> strict < keeps first occurrence.
#pragma unroll
        for (int nt = 0; nt < 4; ++nt) {
            const int code = K0 + (nt << 4) + col;
            const float en = en_s[code];
#pragma unroll
            for (int mt = 0; mt < 2; ++mt)
#pragma unroll
                for (int reg = 0; reg < 4; ++reg) {
                    const float d = fmaf(-2.f, acc[mt][nt][reg], en);
                    const int s = (mt << 2) + reg;
                    if (d < B1[s])      { B2[s] = B1[s]; I2[s] = I1[s]; B1[s] = d; I1[s] = code; }
                    else if (d < B2[s]) { B2[s] = d; I2[s] = code; }
                }
        }
    }

    // ---- Phase 2: cross-lane top-2 butterfly over col bits (disjoint code
    // sets per lane; ties -> lower index = first occurrence) ----
#pragma unroll
    for (int off = 1; off <= 8; off <<= 1) {
#pragma unroll
        for (int s = 0; s < 8; ++s) {
            const float ob1 = __shfl_xor(B1[s], off, 64);
            const int   oi1 = __shfl_xor(I1[s], off, 64);
            const float ob2 = __shfl_xor(B2[s], off, 64);
            const int   oi2 = __shfl_xor(I2[s], off, 64);
            if (ob1 < B1[s] || (ob1 == B1[s] && oi1 < I1[s])) {
                float nb2; int ni2;
                if (B1[s] < ob2 || (B1[s] == ob2 && I1[s] < oi2)) { nb2 = B1[s]; ni2 = I1[s]; }
                else                                              { nb2 = ob2;  ni2 = oi2; }
                B1[s] = ob1; I1[s] = oi1; B2[s] = nb2; I2[s] = ni2;
            } else if (ob1 < B2[s] || (ob1 == B2[s] && oi1 < I2[s])) {
                B2[s] = ob1; I2[s] = oi1;
            }
        }
    }
    if (col == 0) {
#pragma unroll
        for (int s = 0; s < 8; ++s) {
            const int row = mb + ((s >> 2) << 4) + (quad << 2) + (s & 3);
            b1s[row] = B1[s]; b2s[row] = B2[s]; i1s[row] = I1[s]; i2s[row] = I2[s];
        }
    }
    __syncthreads();

    // ---- Phase 3: per-row finalize: fp64 rescue (exact x from global), idx ----
    if (t < 128) {
        const int r  = t;
        const int bh = 2 * blk + (r >> 6);
        const int bb = bh >> 6, hh = bh & 63, ww = r & 63;
        const float* xp = x_in + ((size_t)bb * CHW + (size_t)hh * 64 + ww);
        float b1 = b1s[r], b2 = b2s[r];
        int   i1 = i1s[r], i2 = i2s[r];
        if (b2 - b1 < 1e-2f) {   // split-bf16 noise ~2e-4; rescue near-ties exactly
            const float* e1p = emb + ((size_t)i1 << 6);
            const float* e2p = emb + ((size_t)i2 << 6);
            double d1 = 0.0, d2 = 0.0;
            for (int c = 0; c < 64; ++c) {
                const double xv = (double)xp[(size_t)c * HW];
                const double t1 = xv - (double)e1p[c];
                const double t2 = xv - (double)e2p[c];
                d1 = fma(t1, t1, d1);
                d2 = fma(t2, t2, d2);
            }
            if (d2 < d1 || (d2 == d1 && i2 < i1)) i1 = i2;
        }
        qidx[r] = i1;
        atomicAdd(&hist[i1], 1u);
        idx_out[(blk << 7) + r] = (float)i1;
    }
    __syncthreads();

    // ---- Phase 4: epilogue: quantized out (coalesced along w) + fp64 SSE ----
    {
        const int r  = t & 127;
        const int ch = t >> 7;
        const int bh = 2 * blk + (r >> 6);
        const int bb = bh >> 6, hh = bh & 63, ww = r & 63;
        const size_t base = (size_t)bb * CHW + (size_t)hh * 64 + ww;
        const float* xp = x_in + base;
        float*       op = out + base;
        const float* eq = emb + ((size_t)qidx[r] << 6);
        const int c0 = ch << 5;
        double sse_local = 0.0;
#pragma unroll
        for (int cc = 0; cc < 32; ++cc) {
            const int c = c0 + cc;
            const float qc = eq[c];
            const float dx = qc - xp[(size_t)c * HW];
            sse_local += (double)dx * (double)dx;
            op[(size_t)c * HW] = qc;
        }
#pragma unroll
        for (int off = 32; off > 0; off >>= 1)
            sse_local += __shfl_down(sse_local, off, 64);
        if (lane == 0) ls_red[wv] = sse_local;
        __syncthreads();
        if (t == 0)
            atomicAdd(sse_acc, (ls_red[0] + ls_red[1]) + (ls_red[2] + ls_red[3]));
    }

    // ---- Phase 5: last block computes the scalars ----
    if (t == 0) {
        __threadfence();
        const unsigned old = atomicAdd(done, 1u);
        ls_flag = (old == 511u) ? 1 : 0;
    }
    __syncthreads();
    if (ls_flag) {
        __threadfence();
        double term = 0.0; int act = 0;
#pragma unroll
        for (int j = 0; j < 2; ++j) {
            const int k = t + (j << 8);
            const unsigned cnt = atomicAdd(&hist[k], 0u);  // coherent read
            const double p = (double)cnt / 65536.0;
            term += p * log(p + 1e-10);
            act  += (weight[k] >= 0.01f) ? 1 : 0;
        }
#pragma unroll
        for (int off = 32; off > 0; off >>= 1) {
            term += __shfl_down(term, off, 64);
            act  += __shfl_down(act,  off, 64);
        }
        if (lane == 0) { ls_red[wv] = term; ls_ired[wv] = act; }
        __syncthreads();
        if (t == 0) {
            const double s = (ls_red[0] + ls_red[1]) + (ls_red[2] + ls_red[3]);
            const int    a = ls_ired[0] + ls_ired[1] + ls_ired[2] + ls_ired[3];
            const double sse_tot = atomicAdd(sse_acc, 0.0);
            scal[0] = (float)(sse_tot / 4194304.0);  // commitment_loss
            scal[1] = (float)exp(-s);                // perplexity
            scal[2] = (float)a;                      // active_codes
        }
    }
}

extern "C" void kernel_launch(void* const* d_in, const int* in_sizes, int n_in,
                              void* d_out, int out_size, void* d_ws, size_t ws_size,
                              hipStream_t stream) {
    const float* x      = (const float*)d_in[0];  // [16,64,64,64] fp32
    const float* emb    = (const float*)d_in[1];  // [512,64] fp32
    const float* weight = (const float*)d_in[2];  // [512] fp32

    float* out = (float*)d_out;
    unsigned* hist = (unsigned*)d_ws;
    double*   sse  = (double*)((char*)d_ws + 2048);
    unsigned* done = (unsigned*)((char*)d_ws + 2056);

    float* scal    = out + OUT_ELEMS;      // commitment, perplexity, active
    float* idx_out = out + OUT_ELEMS + 3;  // indices as float [65536]

    hipMemsetAsync(d_ws, 0, 4096, stream);  // zero hist/sse/done (capture-legal)
    vq_fused<<<512, 256, 0, stream>>>(x, emb, weight, out, idx_out, hist, sse,
                                      done, scal);
}